// Round 1
// baseline (2652.259 us; speedup 1.0000x reference)
//
#include <hip/hip_runtime.h>
#include <stdint.h>

#define N_B    32768
#define MLPOUT 1056
#define NPAD3  1152

typedef __attribute__((ext_vector_type(8))) __bf16 bf16x8;
typedef __attribute__((ext_vector_type(4))) float  f32x4;

__device__ __forceinline__ uint16_t f2bf(float f){
  union { float f; uint32_t u; } v; v.f = f;
  return (uint16_t)((v.u + 0x7fffu + ((v.u >> 16) & 1u)) >> 16);
}
__device__ __forceinline__ float bf2f(uint16_t h){
  union { uint32_t u; float f; } v; v.u = ((uint32_t)h) << 16; return v.f;
}
__device__ __forceinline__ void gld_lds16(const void* gp, void* lp){
  __builtin_amdgcn_global_load_lds(
    (__attribute__((address_space(1))) void*)(void*)gp,
    (__attribute__((address_space(3))) void*)lp, 16, 0, 0);
}

// ---------------- k0a: f32 [K][N] -> bf16 [Npad][K] transpose+cast ----------------
__global__ void transpose_cast_kernel(const float* __restrict__ in, uint16_t* __restrict__ out,
                                      int K, int N, int Npad)
{
  __shared__ float tile[32][33];
  const int tx = threadIdx.x & 31, ty = threadIdx.x >> 5;
  const int k0 = blockIdx.x * 32, n0 = blockIdx.y * 32;
#pragma unroll
  for (int i = 0; i < 4; i++){
    int k = k0 + ty + i*8, nn = n0 + tx;
    float v = (k < K && nn < N) ? in[(size_t)k*N + nn] : 0.0f;
    tile[ty + i*8][tx] = v;
  }
  __syncthreads();
#pragma unroll
  for (int i = 0; i < 4; i++){
    int nn = n0 + ty + i*8, k = k0 + tx;
    if (nn < Npad && k < K) out[(size_t)nn*K + k] = f2bf(tile[tx][ty + i*8]);
  }
}

// ---------------- k0b: Wbig = [W_Z1@W_Z2[0:32]; W_Z2[32:160]; W_Z2[160]] (packed 193x32 f32), b3 pad ----
__global__ void prep_small_kernel(const float* __restrict__ W_Z1, const float* __restrict__ W_Z2,
                                  const float* __restrict__ b3, float* __restrict__ Wbig,
                                  float* __restrict__ b3p)
{
  const int tid = threadIdx.x;
  for (int idx = tid; idx < 193*32; idx += 256){
    int r = idx >> 5, cc = idx & 31;
    float v;
    if (r < 64){
      v = 0.f;
      for (int i = 0; i < 32; i++) v += W_Z1[r*32 + i] * W_Z2[i*32 + cc];
    } else if (r < 192) v = W_Z2[(r - 32)*32 + cc];
    else                v = W_Z2[160*32 + cc];
    Wbig[idx] = v;
  }
  for (int idx = tid; idx < NPAD3; idx += 256)
    b3p[idx] = (idx < MLPOUT) ? b3[idx] : 0.0f;
}

// ---------------- k1: prologue (wave-per-sample, f32) ----------------
// per b: h=h0@W_h1+b, hm=relu([h,m_h]), gate, Zm=[Z0row,m_Zrow]@Wbig + g-fixup(n==2),
//        M=Zm^T Zm, F=||M||+1; writes Mcat=[M|hm] bf16, Zm f32 -> d_out MZ region, Fn.
__global__ __launch_bounds__(256)
void prologue_kernel(const float* __restrict__ Z0, const float* __restrict__ h0,
                     const float* __restrict__ mZ, const float* __restrict__ mh,
                     const float* __restrict__ W_h1, const float* __restrict__ b_h1,
                     const float* __restrict__ W_g1a, const float* __restrict__ b_g1a,
                     const float* __restrict__ W_g1b, const float* __restrict__ b_g1b,
                     const float* __restrict__ WbigG,
                     uint16_t* __restrict__ Mcat, float* __restrict__ Fn,
                     float* __restrict__ ZmOut)
{
  // wbig LDS layout: 4 h-sections of 48 rows, stride 32, section base h*1544 (bank-offset 8/section);
  // row 192 (g-fixup weights) at [6176..6208)
  __shared__ __align__(16) float wbig[6208];
  __shared__ float h0s[4][128];
  __shared__ float hms[4][160];
  __shared__ __align__(16) float zms[4][16*36];
  const int tid = threadIdx.x, w = tid >> 6, l = tid & 63;

  for (int d = tid; d < 6208; d += 256){
    float v;
    if (d < 6176){
      int hh = d / 1544, rem = d - hh*1544;
      int r = rem >> 5, cc = rem & 31;
      v = (r < 48) ? WbigG[(hh*48 + r)*32 + cc] : 0.0f;
    } else v = WbigG[6144 + (d - 6176)];
    wbig[d] = v;
  }
  __syncthreads();

  const int n  = l & 15, h  = l >> 4;   // Zm phase roles
  const int cg = l & 31, kh = l >> 5;   // h/gate phase roles

  for (int bi = 0; bi < 4; bi++){
    const int b = (blockIdx.x << 4) + (w << 2) + bi;

    // X = [Z0 row (64) | m_Z row (128)], lane holds 48-slice [48h, 48h+48)
    const float* z0p = Z0 + (size_t)b*1024 + n*64;
    const float* mzp = mZ + (size_t)b*2048 + n*128;
    float Xs[48];
#pragma unroll
    for (int j4 = 0; j4 < 12; j4++){
      int k = h*48 + j4*4;
      const float* p = (k < 64) ? (z0p + k) : (mzp + (k - 64));
      float4 t = *(const float4*)p;
      Xs[j4*4+0]=t.x; Xs[j4*4+1]=t.y; Xs[j4*4+2]=t.z; Xs[j4*4+3]=t.w;
    }

    // ---- h, hm, gate ----
    h0s[w][l]      = h0[(size_t)b*128 + l];
    h0s[w][l + 64] = h0[(size_t)b*128 + 64 + l];
    float mh0 = mh[(size_t)b*128 + l];
    float mh1 = mh[(size_t)b*128 + 64 + l];
    float hacc = 0.f;
#pragma unroll 16
    for (int i = 0; i < 64; i++)
      hacc += h0s[w][kh*64 + i] * W_h1[(kh*64 + i)*32 + cg];
    hacc += __shfl_xor(hacc, 32);
    float hmc  = fmaxf(hacc + b_h1[cg], 0.f);
    float hm32 = fmaxf(mh0, 0.f), hm96 = fmaxf(mh1, 0.f);
    if (l < 32) hms[w][l] = hmc;
    hms[w][32 + l] = hm32;
    hms[w][96 + l] = hm96;
    uint16_t* mch = Mcat + (size_t)b*1184 + 1024;
    if (l < 32) mch[l] = f2bf(hmc);
    mch[32 + l] = f2bf(hm32);
    mch[96 + l] = f2bf(hm96);
    float tacc = 0.f;
#pragma unroll 16
    for (int i = 0; i < 80; i++){
      int k = kh*80 + i;
      tacc += hms[w][k] * W_g1a[k*32 + cg];
    }
    tacc += __shfl_xor(tacc, 32);
    float tc = fmaxf(tacc + b_g1a[cg], 0.f);
    float gp = (l < 32) ? tc * W_g1b[cg] : 0.f;
#pragma unroll
    for (int s = 1; s < 64; s <<= 1) gp += __shfl_xor(gp, s);
    const float g = gp + b_g1b[0];

    // ---- Zm (f32, register-tiled K=192) ----
    float za[32];
#pragma unroll
    for (int c = 0; c < 32; c++) za[c] = 0.f;
    const float* wsec = &wbig[h*1544];
#pragma unroll
    for (int j = 0; j < 48; j++){
      float xv = Xs[j];
      const float4* wrow = (const float4*)(wsec + j*32);
#pragma unroll
      for (int q = 0; q < 8; q++){
        float4 wv = wrow[q];
        za[q*4+0] += xv * wv.x;
        za[q*4+1] += xv * wv.y;
        za[q*4+2] += xv * wv.z;
        za[q*4+3] += xv * wv.w;
      }
    }
#pragma unroll
    for (int c = 0; c < 32; c++){
      za[c] += __shfl_xor(za[c], 16);
      za[c] += __shfl_xor(za[c], 32);
    }
    if (n == 2){
#pragma unroll
      for (int c = 0; c < 32; c++) za[c] += g * wbig[6176 + c];
    }
    if (h == 0){
#pragma unroll
      for (int c = 0; c < 32; c++) zms[w][n*36 + c] = za[c];
      float4* zo = (float4*)(ZmOut + (size_t)b*512 + n*32);
#pragma unroll
      for (int q = 0; q < 8; q++)
        zo[q] = make_float4(za[q*4], za[q*4+1], za[q*4+2], za[q*4+3]);
    }

    // ---- M = Zm^T Zm, F_norm, Mcat[0:1024] ----
    const int jj = l & 31, ih = l >> 5;
    float macc[16];
#pragma unroll
    for (int i = 0; i < 16; i++) macc[i] = 0.f;
#pragma unroll
    for (int nn = 0; nn < 16; nn++){
      float zj = zms[w][nn*36 + jj];
      const float4* zi = (const float4*)&zms[w][nn*36 + ih*16];
#pragma unroll
      for (int q = 0; q < 4; q++){
        float4 zv = zi[q];
        macc[q*4+0] += zj * zv.x;
        macc[q*4+1] += zj * zv.y;
        macc[q*4+2] += zj * zv.z;
        macc[q*4+3] += zj * zv.w;
      }
    }
    float fs = 0.f;
#pragma unroll
    for (int i = 0; i < 16; i++) fs += macc[i]*macc[i];
#pragma unroll
    for (int s = 1; s < 64; s <<= 1) fs += __shfl_xor(fs, s);
    if (l == 0) Fn[b] = sqrtf(fs) + 1.0f;
    uint16_t* mcb = Mcat + (size_t)b*1184;
#pragma unroll
    for (int ii = 0; ii < 16; ii++)
      mcb[(ih*16 + ii)*32 + jj] = f2bf(macc[ii]);
  }
}

// ---------------- k2..k4: 128x128 bf16 MFMA GEMM (m97 structure) ----------------
// A row-major [M][K] bf16, Bt row-major [N][K] bf16 (K contiguous both sides).
// MODE 0: outB bf16 = act(A@B^T + bias), stride 1024.
// MODE 1: cols<1024 -> outB bf16 (undivided); 1024..1055 -> outF f32 = v/Fn[row]; else skip.
template<int KSTEPS, int RELU, int MODE>
__global__ __launch_bounds__(256)
void gemm_kernel(const uint16_t* __restrict__ A, const uint16_t* __restrict__ Bt,
                 const float* __restrict__ bias, uint16_t* __restrict__ outB,
                 float* __restrict__ outF, const float* __restrict__ Fn)
{
  constexpr int K = KSTEPS * 32;
  __shared__ uint16_t As[2][128*32];
  __shared__ uint16_t Bs[2][128*32];
  const int tid = threadIdx.x;
  const int w = tid >> 6, lane = tid & 63;
  const int wr = w >> 1, wc = w & 1;
  const int bm = blockIdx.x, bn = blockIdx.y;
  const int lr = lane & 15, lk8 = (lane >> 4) << 3;

  f32x4 acc[4][4];
#pragma unroll
  for (int r = 0; r < 4; r++)
#pragma unroll
    for (int c = 0; c < 4; c++) acc[r][c] = (f32x4)(0.0f);

  const size_t arow0 = (size_t)bm * 128;
  const size_t brow0 = (size_t)bn * 128;

#define STAGE(buf, ks) do { \
    int k0_ = (ks) * 32; \
    _Pragma("unroll") \
    for (int i_ = 0; i_ < 2; i_++){ \
      int C_ = i_*256 + tid; \
      int row_ = C_ >> 2, c8_ = C_ & 3; \
      gld_lds16(A  + (arow0 + row_) * K + k0_ + c8_*8, &As[buf][(i_*256 + w*64)*8]); \
      gld_lds16(Bt + (brow0 + row_) * K + k0_ + c8_*8, &Bs[buf][(i_*256 + w*64)*8]); \
    } } while(0)

  STAGE(0, 0);
  __syncthreads();
  for (int ks = 0; ks < KSTEPS; ks++){
    int cur = ks & 1;
    if (ks + 1 < KSTEPS) STAGE(cur ^ 1, ks + 1);
    bf16x8 af[4], bfv[4];
#pragma unroll
    for (int r = 0; r < 4; r++){
      uint4 t = *(const uint4*)&As[cur][(wr*64 + r*16 + lr)*32 + lk8];
      af[r] = __builtin_bit_cast(bf16x8, t);
    }
#pragma unroll
    for (int c = 0; c < 4; c++){
      uint4 t = *(const uint4*)&Bs[cur][(wc*64 + c*16 + lr)*32 + lk8];
      bfv[c] = __builtin_bit_cast(bf16x8, t);
    }
#pragma unroll
    for (int r = 0; r < 4; r++)
#pragma unroll
      for (int c = 0; c < 4; c++)
        acc[r][c] = __builtin_amdgcn_mfma_f32_16x16x32_bf16(af[r], bfv[c], acc[r][c], 0, 0, 0);
    __syncthreads();
  }
#undef STAGE

#pragma unroll
  for (int c = 0; c < 4; c++){
    int gcol = bn*128 + wc*64 + c*16 + lr;
    float bv = bias[gcol];
#pragma unroll
    for (int r = 0; r < 4; r++){
      int rowb = bm*128 + wr*64 + r*16 + ((lane >> 4) << 2);
#pragma unroll
      for (int gg = 0; gg < 4; gg++){
        int grow = rowb + gg;
        float v = acc[r][c][gg] + bv;
        if (RELU) v = fmaxf(v, 0.0f);
        if (MODE == 0){
          outB[(size_t)grow*1024 + gcol] = f2bf(v);
        } else {
          if (gcol < 1024)       outB[(size_t)grow*1024 + gcol] = f2bf(v);
          else if (gcol < 1056)  outF[(size_t)grow*32 + (gcol - 1024)] = v / Fn[grow];
        }
      }
    }
  }
}

// ---------------- k5: M_Z = (Zm @ M_Zflat) / F  (reads+overwrites d_out MZ region) ----------------
__global__ __launch_bounds__(256)
void epilogue_kernel(const uint16_t* __restrict__ Mzf, const float* __restrict__ Fn,
                     float* __restrict__ Out)
{
  __shared__ __align__(16) uint16_t mzS[4][1024];
  __shared__ __align__(16) float    zmS[4][16*36];
  const int tid = threadIdx.x, w = tid >> 6, l = tid & 63;
  const int n = l & 15, q = l >> 4;
  for (int bi = 0; bi < 4; bi++){
    const int b = (blockIdx.x << 4) + (w << 2) + bi;
    const uint4* src = (const uint4*)(Mzf + (size_t)b*1024);
    uint4* dst = (uint4*)&mzS[w][0];
    dst[l]      = src[l];
    dst[l + 64] = src[l + 64];
    const float4* zsrc = (const float4*)(Out + (size_t)b*512);
#pragma unroll
    for (int i = 0; i < 2; i++){
      int f = i*64 + l;
      int nn = f >> 3, c4 = f & 7;
      *(float4*)&zmS[w][nn*36 + c4*4] = zsrc[f];
    }
    float acc[8];
#pragma unroll
    for (int i = 0; i < 8; i++) acc[i] = 0.f;
#pragma unroll
    for (int j = 0; j < 32; j++){
      float zv = zmS[w][n*36 + j];
      uint4 mv = *(const uint4*)&mzS[w][j*32 + q*8];
      acc[0] += zv * bf2f((uint16_t)(mv.x & 0xffffu));
      acc[1] += zv * bf2f((uint16_t)(mv.x >> 16));
      acc[2] += zv * bf2f((uint16_t)(mv.y & 0xffffu));
      acc[3] += zv * bf2f((uint16_t)(mv.y >> 16));
      acc[4] += zv * bf2f((uint16_t)(mv.z & 0xffffu));
      acc[5] += zv * bf2f((uint16_t)(mv.z >> 16));
      acc[6] += zv * bf2f((uint16_t)(mv.w & 0xffffu));
      acc[7] += zv * bf2f((uint16_t)(mv.w >> 16));
    }
    const float inv = 1.0f / Fn[b];
    float4* op = (float4*)(Out + (size_t)b*512 + n*32 + q*8);
    op[0] = make_float4(acc[0]*inv, acc[1]*inv, acc[2]*inv, acc[3]*inv);
    op[1] = make_float4(acc[4]*inv, acc[5]*inv, acc[6]*inv, acc[7]*inv);
  }
}

// ---------------- launch ----------------
extern "C" void kernel_launch(void* const* d_in, const int* in_sizes, int n_in,
                              void* d_out, int out_size, void* d_ws, size_t ws_size,
                              hipStream_t stream)
{
  const float* Z0    = (const float*)d_in[0];
  const float* h0    = (const float*)d_in[1];
  const float* mZ    = (const float*)d_in[2];
  const float* mh    = (const float*)d_in[3];
  const float* W_Z1  = (const float*)d_in[4];
  const float* W_h1  = (const float*)d_in[5];
  const float* b_h1  = (const float*)d_in[6];
  const float* W_g1a = (const float*)d_in[7];
  const float* b_g1a = (const float*)d_in[8];
  const float* W_g1b = (const float*)d_in[9];
  const float* b_g1b = (const float*)d_in[10];
  const float* W_Z2  = (const float*)d_in[11];
  const float* W1    = (const float*)d_in[12];
  const float* b1    = (const float*)d_in[13];
  const float* W2    = (const float*)d_in[14];
  const float* b2    = (const float*)d_in[15];
  const float* W3    = (const float*)d_in[16];
  const float* b3    = (const float*)d_in[17];

  char* ws = (char*)d_ws;
  size_t off = 0;
  auto alloc = [&](size_t bytes) -> char* {
    char* p = ws + off;
    off += (bytes + 255) & ~(size_t)255;
    return p;
  };
  uint16_t* W1t  = (uint16_t*)alloc((size_t)1024*1184*2);
  uint16_t* W2t  = (uint16_t*)alloc((size_t)1024*1024*2);
  uint16_t* W3t  = (uint16_t*)alloc((size_t)NPAD3*1024*2);
  float*    b3p  = (float*)   alloc((size_t)NPAD3*4);
  float*    Wbig = (float*)   alloc((size_t)193*32*4);
  float*    Fn   = (float*)   alloc((size_t)N_B*4);
  uint16_t* Mcat = (uint16_t*)alloc((size_t)N_B*1184*2);
  uint16_t* H1   = (uint16_t*)alloc((size_t)N_B*1024*2);
  uint16_t* H2   = (uint16_t*)alloc((size_t)N_B*1024*2);
  uint16_t* Mzf  = Mcat;                          // Mcat dead after GEMM1 -> reuse
  float* OutMZ = (float*)d_out;
  float* OutMH = (float*)d_out + (size_t)N_B*512;

  transpose_cast_kernel<<<dim3(37,32), 256, 0, stream>>>(W1, W1t, 1184, 1024, 1024);
  transpose_cast_kernel<<<dim3(32,32), 256, 0, stream>>>(W2, W2t, 1024, 1024, 1024);
  transpose_cast_kernel<<<dim3(32,36), 256, 0, stream>>>(W3, W3t, 1024, 1056, NPAD3);
  prep_small_kernel<<<1, 256, 0, stream>>>(W_Z1, W_Z2, b3, Wbig, b3p);
  prologue_kernel<<<2048, 256, 0, stream>>>(Z0, h0, mZ, mh, W_h1, b_h1, W_g1a, b_g1a,
                                            W_g1b, b_g1b, Wbig, Mcat, Fn, OutMZ);
  gemm_kernel<37,1,0><<<dim3(256,8), 256, 0, stream>>>(Mcat, W1t, b1, H1, nullptr, nullptr);
  gemm_kernel<32,1,0><<<dim3(256,8), 256, 0, stream>>>(H1,   W2t, b2, H2, nullptr, nullptr);
  gemm_kernel<32,0,1><<<dim3(256,9), 256, 0, stream>>>(H2,   W3t, b3p, Mzf, OutMH, Fn);
  epilogue_kernel<<<2048, 256, 0, stream>>>(Mzf, Fn, OutMZ);
}

// Round 2
// 685.793 us; speedup vs baseline: 3.8674x; 3.8674x over previous
//
#include <hip/hip_runtime.h>
#include <stdint.h>

#define N_B    32768
#define MLPOUT 1056
#define NPAD3  1152

typedef __attribute__((ext_vector_type(8)))  __bf16 bf16x8;
typedef __attribute__((ext_vector_type(4)))  float  f32x4;
typedef __attribute__((ext_vector_type(16))) float  f32x16;

__device__ __forceinline__ uint16_t f2bf(float f){
  union { float f; uint32_t u; } v; v.f = f;
  return (uint16_t)((v.u + 0x7fffu + ((v.u >> 16) & 1u)) >> 16);
}
__device__ __forceinline__ float bf2f(uint16_t h){
  union { uint32_t u; float f; } v; v.u = ((uint32_t)h) << 16; return v.f;
}
__device__ __forceinline__ void gld_lds16(const void* gp, void* lp){
  __builtin_amdgcn_global_load_lds(
    (__attribute__((address_space(1))) void*)(void*)gp,
    (__attribute__((address_space(3))) void*)lp, 16, 0, 0);
}

// ---------------- k0a: f32 [K][N] -> bf16 [Npad][K] transpose+cast ----------------
__global__ void transpose_cast_kernel(const float* __restrict__ in, uint16_t* __restrict__ out,
                                      int K, int N, int Npad)
{
  __shared__ float tile[32][33];
  const int tx = threadIdx.x & 31, ty = threadIdx.x >> 5;
  const int k0 = blockIdx.x * 32, n0 = blockIdx.y * 32;
#pragma unroll
  for (int i = 0; i < 4; i++){
    int k = k0 + ty + i*8, nn = n0 + tx;
    float v = (k < K && nn < N) ? in[(size_t)k*N + nn] : 0.0f;
    tile[ty + i*8][tx] = v;
  }
  __syncthreads();
#pragma unroll
  for (int i = 0; i < 4; i++){
    int nn = n0 + ty + i*8, k = k0 + tx;
    if (nn < Npad && k < K) out[(size_t)nn*K + k] = f2bf(tile[tx][ty + i*8]);
  }
}

// ---------------- k0b: fused W -> pre-packed MFMA B-fragments (hi/lo bf16) ----------------
// Wfull[k][c], k=0..191: rows 0..63 = W_Z1@W_Z2[0:32], rows 64..191 = W_Z2[32:160].
// Fragment layout: Wf[(kk*2+ct)*64*8 + lane*8 + j] = Wfull[kk*32+(lane>>4)*8+j][ct*16+(lane&15)]
__global__ void prep_small_kernel(const float* __restrict__ W_Z1, const float* __restrict__ W_Z2,
                                  const float* __restrict__ b3,
                                  uint16_t* __restrict__ WfH, uint16_t* __restrict__ WfL,
                                  float* __restrict__ wgG, float* __restrict__ b3p)
{
  __shared__ float wl[192*32];
  const int tid = threadIdx.x;
  for (int idx = tid; idx < 6144; idx += 256){
    int r = idx >> 5, c = idx & 31;
    float v;
    if (r < 64){
      v = 0.f;
      for (int i = 0; i < 32; i++) v += W_Z1[r*32 + i] * W_Z2[i*32 + c];
    } else v = W_Z2[(r - 32)*32 + c];
    wl[idx] = v;
  }
  __syncthreads();
  for (int q = tid; q < 768; q += 256){            // q = (kk*2+ct)*64 + lane
    int lane = q & 63, ctkk = q >> 6;
    int ct = ctkk & 1, kk = ctkk >> 1;
    int c  = ct*16 + (lane & 15);
    int k0 = kk*32 + ((lane >> 4) << 3);
    for (int j = 0; j < 8; j++){
      float v = wl[(k0 + j)*32 + c];
      uint16_t hb = f2bf(v);
      WfH[q*8 + j] = hb;
      WfL[q*8 + j] = f2bf(v - bf2f(hb));
    }
  }
  if (tid < 32) wgG[tid] = W_Z2[160*32 + tid];     // g-fixup row (f32)
  for (int idx = tid; idx < NPAD3; idx += 256)
    b3p[idx] = (idx < MLPOUT) ? b3[idx] : 0.0f;
}

// ---------------- P1: h / hm / gate (weights in LDS, wave-per-sample) ----------------
__global__ __launch_bounds__(256)
void gate_kernel(const float* __restrict__ h0, const float* __restrict__ mh,
                 const float* __restrict__ W_h1, const float* __restrict__ b_h1,
                 const float* __restrict__ W_g1a, const float* __restrict__ b_g1a,
                 const float* __restrict__ W_g1b, const float* __restrict__ b_g1b,
                 uint16_t* __restrict__ Mcat, float* __restrict__ gateOut)
{
  __shared__ float wh[128*32];
  __shared__ float wg[160*32];
  __shared__ float wgb[32], bh[32], bga[32];
  __shared__ float bgb;
  __shared__ float hrow[4][128];
  __shared__ float hms[4][160];
  const int tid = threadIdx.x, w = tid >> 6, l = tid & 63;
  for (int i = tid; i < 4096; i += 256) wh[i] = W_h1[i];
  for (int i = tid; i < 5120; i += 256) wg[i] = W_g1a[i];
  if (tid < 32){ wgb[tid] = W_g1b[tid]; bh[tid] = b_h1[tid]; bga[tid] = b_g1a[tid]; }
  if (tid == 0) bgb = b_g1b[0];
  __syncthreads();
  const int cg = l & 31, kh = l >> 5;
  for (int bi = 0; bi < 16; bi++){
    const int b = blockIdx.x*64 + w*16 + bi;
    hrow[w][l]      = h0[(size_t)b*128 + l];
    hrow[w][64 + l] = h0[(size_t)b*128 + 64 + l];
    float mh0 = mh[(size_t)b*128 + l];
    float mh1 = mh[(size_t)b*128 + 64 + l];
    float hacc = 0.f;
#pragma unroll 16
    for (int i = 0; i < 64; i++){
      int k = kh*64 + i;
      hacc += hrow[w][k] * wh[k*32 + cg];
    }
    hacc += __shfl_xor(hacc, 32);
    float hmc = fmaxf(hacc + bh[cg], 0.f);
    float r0 = fmaxf(mh0, 0.f), r1 = fmaxf(mh1, 0.f);
    if (l < 32) hms[w][l] = hmc;
    hms[w][32 + l] = r0;
    hms[w][96 + l] = r1;
    uint16_t* mc = Mcat + (size_t)b*1184 + 1024;
    if (l < 32) mc[l] = f2bf(hmc);
    mc[32 + l] = f2bf(r0);
    mc[96 + l] = f2bf(r1);
    float tacc = 0.f;
#pragma unroll 16
    for (int i = 0; i < 80; i++){
      int k = kh*80 + i;
      tacc += hms[w][k] * wg[k*32 + cg];
    }
    tacc += __shfl_xor(tacc, 32);
    float tc = fmaxf(tacc + bga[cg], 0.f);
    float gp = (l < 32) ? tc * wgb[cg] : 0.f;
#pragma unroll
    for (int s = 1; s < 64; s <<= 1) gp += __shfl_xor(gp, s);
    if (l == 0) gateOut[b] = gp + bgb;
  }
}

// ---------------- P2: Zm (MFMA, hi/lo compensated) + gram (MFMA) + F + writes ----------------
__global__ __launch_bounds__(256)
void zm_gram_kernel(const float* __restrict__ Z0, const float* __restrict__ mZ,
                    const uint16_t* __restrict__ WfH, const uint16_t* __restrict__ WfL,
                    const float* __restrict__ wgG, const float* __restrict__ gateB,
                    uint16_t* __restrict__ Mcat, float* __restrict__ Fn,
                    float* __restrict__ ZmOut)
{
  __shared__ __align__(16) uint16_t wfh[6144], wfl[6144];
  __shared__ float wgs[32];
  __shared__ __align__(16) uint16_t zhS[4][32*24], zlS[4][32*24];  // col-major [c][row], pad 24
  const int tid = threadIdx.x, w = tid >> 6, l = tid & 63;
#pragma unroll
  for (int i = 0; i < 3; i++){
    gld_lds16(WfH + (i*256 + tid)*8, &wfh[(i*256 + w*64)*8]);
    gld_lds16(WfL + (i*256 + tid)*8, &wfl[(i*256 + w*64)*8]);
  }
  if (tid < 32) wgs[tid] = wgG[tid];
  __syncthreads();
  const int n = l & 15, sl = l >> 4;
  for (int bi = 0; bi < 4; bi++){
    const int b = (blockIdx.x << 4) + (w << 2) + bi;
    // ---- load X row n, k-slice sl*8, as hi/lo bf16 fragments ----
    bf16x8 xh[6], xl[6];
    const float* zp = Z0 + (size_t)b*1024 + n*64  + sl*8;
    const float* mp = mZ + (size_t)b*2048 + n*128 + sl*8;
#pragma unroll
    for (int kk = 0; kk < 6; kk++){
      const float* src = (kk < 2) ? (zp + kk*32) : (mp + (kk - 2)*32);
      float x[8];
      *(float4*)&x[0] = *(const float4*)src;
      *(float4*)&x[4] = *(const float4*)(src + 4);
#pragma unroll
      for (int j = 0; j < 8; j++){
        __bf16 h = (__bf16)x[j];
        xh[kk][j] = h;
        xl[kk][j] = (__bf16)(x[j] - (float)h);
      }
    }
    // ---- Zm = X @ Wfull (compensated) ----
    f32x4 za[2];
    za[0] = (f32x4)(0.f); za[1] = (f32x4)(0.f);
#pragma unroll
    for (int kk = 0; kk < 6; kk++){
#pragma unroll
      for (int ct = 0; ct < 2; ct++){
        bf16x8 whf = *(const bf16x8*)&wfh[((kk*2 + ct)*64 + l)*8];
        bf16x8 wlf = *(const bf16x8*)&wfl[((kk*2 + ct)*64 + l)*8];
        za[ct] = __builtin_amdgcn_mfma_f32_16x16x32_bf16(xh[kk], whf, za[ct], 0, 0, 0);
        za[ct] = __builtin_amdgcn_mfma_f32_16x16x32_bf16(xl[kk], whf, za[ct], 0, 0, 0);
        za[ct] = __builtin_amdgcn_mfma_f32_16x16x32_bf16(xh[kk], wlf, za[ct], 0, 0, 0);
      }
    }
    // gate fixup: Zm row 2 += g * Wfull[192]  (D rows = sl*4 + r)
    const float g = gateB[b];
    if (sl == 0){
      za[0][2] += g * wgs[n];
      za[1][2] += g * wgs[16 + n];
    }
    // ---- write Zm f32; stash hi/lo bf16 col-major in LDS for gram frags ----
    float* zo = ZmOut + (size_t)b*512;
#pragma unroll
    for (int ct = 0; ct < 2; ct++){
      ushort4 ph, pl;
#pragma unroll
      for (int r = 0; r < 4; r++){
        float v = za[ct][r];
        zo[(sl*4 + r)*32 + ct*16 + n] = v;
        uint16_t hb = f2bf(v);
        ((uint16_t*)&ph)[r] = hb;
        ((uint16_t*)&pl)[r] = f2bf(v - bf2f(hb));
      }
      const int c = ct*16 + n;
      *(ushort4*)&zhS[w][c*24 + sl*4] = ph;
      *(ushort4*)&zlS[w][c*24 + sl*4] = pl;
    }
    // ---- gram M = Zm^T Zm via 32x32x16 (A-frag == B-frag by symmetry), compensated ----
    const int c2 = l & 31, n0 = (l >> 5) << 3;
    bf16x8 zhf = *(const bf16x8*)&zhS[w][c2*24 + n0];
    bf16x8 zlf = *(const bf16x8*)&zlS[w][c2*24 + n0];
    f32x16 gacc = (f32x16)(0.f);
    gacc = __builtin_amdgcn_mfma_f32_32x32x16_bf16(zhf, zhf, gacc, 0, 0, 0);
    gacc = __builtin_amdgcn_mfma_f32_32x32x16_bf16(zlf, zhf, gacc, 0, 0, 0);
    gacc = __builtin_amdgcn_mfma_f32_32x32x16_bf16(zhf, zlf, gacc, 0, 0, 0);
    // ---- F_norm ----
    float fs = 0.f;
#pragma unroll
    for (int i = 0; i < 16; i++) fs += gacc[i]*gacc[i];
#pragma unroll
    for (int s = 1; s < 64; s <<= 1) fs += __shfl_xor(fs, s);
    if (l == 0) Fn[b] = sqrtf(fs) + 1.0f;
    // ---- Mcat M-part (bf16): D layout col=l&31, row=(r&3)+8*(r>>2)+4*(l>>5) ----
    uint16_t* mcb = Mcat + (size_t)b*1184;
#pragma unroll
    for (int r = 0; r < 16; r++){
      int row = (r & 3) + 8*(r >> 2) + 4*(l >> 5);
      mcb[row*32 + c2] = f2bf(gacc[r]);
    }
  }
}

// ---------------- k2..k4: 128x128 bf16 MFMA GEMM (m97 structure) ----------------
template<int KSTEPS, int RELU, int MODE>
__global__ __launch_bounds__(256)
void gemm_kernel(const uint16_t* __restrict__ A, const uint16_t* __restrict__ Bt,
                 const float* __restrict__ bias, uint16_t* __restrict__ outB,
                 float* __restrict__ outF, const float* __restrict__ Fn)
{
  constexpr int K = KSTEPS * 32;
  __shared__ uint16_t As[2][128*32];
  __shared__ uint16_t Bs[2][128*32];
  const int tid = threadIdx.x;
  const int w = tid >> 6, lane = tid & 63;
  const int wr = w >> 1, wc = w & 1;
  const int bm = blockIdx.x, bn = blockIdx.y;
  const int lr = lane & 15, lk8 = (lane >> 4) << 3;

  f32x4 acc[4][4];
#pragma unroll
  for (int r = 0; r < 4; r++)
#pragma unroll
    for (int c = 0; c < 4; c++) acc[r][c] = (f32x4)(0.0f);

  const size_t arow0 = (size_t)bm * 128;
  const size_t brow0 = (size_t)bn * 128;

#define STAGE(buf, ks) do { \
    int k0_ = (ks) * 32; \
    _Pragma("unroll") \
    for (int i_ = 0; i_ < 2; i_++){ \
      int C_ = i_*256 + tid; \
      int row_ = C_ >> 2, c8_ = C_ & 3; \
      gld_lds16(A  + (arow0 + row_) * K + k0_ + c8_*8, &As[buf][(i_*256 + w*64)*8]); \
      gld_lds16(Bt + (brow0 + row_) * K + k0_ + c8_*8, &Bs[buf][(i_*256 + w*64)*8]); \
    } } while(0)

  STAGE(0, 0);
  __syncthreads();
  for (int ks = 0; ks < KSTEPS; ks++){
    int cur = ks & 1;
    if (ks + 1 < KSTEPS) STAGE(cur ^ 1, ks + 1);
    bf16x8 af[4], bfv[4];
#pragma unroll
    for (int r = 0; r < 4; r++){
      uint4 t = *(const uint4*)&As[cur][(wr*64 + r*16 + lr)*32 + lk8];
      af[r] = __builtin_bit_cast(bf16x8, t);
    }
#pragma unroll
    for (int c = 0; c < 4; c++){
      uint4 t = *(const uint4*)&Bs[cur][(wc*64 + c*16 + lr)*32 + lk8];
      bfv[c] = __builtin_bit_cast(bf16x8, t);
    }
#pragma unroll
    for (int r = 0; r < 4; r++)
#pragma unroll
      for (int c = 0; c < 4; c++)
        acc[r][c] = __builtin_amdgcn_mfma_f32_16x16x32_bf16(af[r], bfv[c], acc[r][c], 0, 0, 0);
    __syncthreads();
  }
#undef STAGE

#pragma unroll
  for (int c = 0; c < 4; c++){
    int gcol = bn*128 + wc*64 + c*16 + lr;
    float bv = bias[gcol];
#pragma unroll
    for (int r = 0; r < 4; r++){
      int rowb = bm*128 + wr*64 + r*16 + ((lane >> 4) << 2);
#pragma unroll
      for (int gg = 0; gg < 4; gg++){
        int grow = rowb + gg;
        float v = acc[r][c][gg] + bv;
        if (RELU) v = fmaxf(v, 0.0f);
        if (MODE == 0){
          outB[(size_t)grow*1024 + gcol] = f2bf(v);
        } else {
          if (gcol < 1024)       outB[(size_t)grow*1024 + gcol] = f2bf(v);
          else if (gcol < 1056)  outF[(size_t)grow*32 + (gcol - 1024)] = v / Fn[grow];
        }
      }
    }
  }
}

// ---------------- k5: M_Z = (Zm @ M_Zflat) / F ----------------
__global__ __launch_bounds__(256)
void epilogue_kernel(const uint16_t* __restrict__ Mzf, const float* __restrict__ Fn,
                     float* __restrict__ Out)
{
  __shared__ __align__(16) uint16_t mzS[4][1024];
  __shared__ __align__(16) float    zmS[4][16*36];
  const int tid = threadIdx.x, w = tid >> 6, l = tid & 63;
  const int n = l & 15, q = l >> 4;
  for (int bi = 0; bi < 4; bi++){
    const int b = (blockIdx.x << 4) + (w << 2) + bi;
    const uint4* src = (const uint4*)(Mzf + (size_t)b*1024);
    uint4* dst = (uint4*)&mzS[w][0];
    dst[l]      = src[l];
    dst[l + 64] = src[l + 64];
    const float4* zsrc = (const float4*)(Out + (size_t)b*512);
#pragma unroll
    for (int i = 0; i < 2; i++){
      int f = i*64 + l;
      int nn = f >> 3, c4 = f & 7;
      *(float4*)&zmS[w][nn*36 + c4*4] = zsrc[f];
    }
    float acc[8];
#pragma unroll
    for (int i = 0; i < 8; i++) acc[i] = 0.f;
#pragma unroll
    for (int j = 0; j < 32; j++){
      float zv = zmS[w][n*36 + j];
      uint4 mv = *(const uint4*)&mzS[w][j*32 + q*8];
      acc[0] += zv * bf2f((uint16_t)(mv.x & 0xffffu));
      acc[1] += zv * bf2f((uint16_t)(mv.x >> 16));
      acc[2] += zv * bf2f((uint16_t)(mv.y & 0xffffu));
      acc[3] += zv * bf2f((uint16_t)(mv.y >> 16));
      acc[4] += zv * bf2f((uint16_t)(mv.z & 0xffffu));
      acc[5] += zv * bf2f((uint16_t)(mv.z >> 16));
      acc[6] += zv * bf2f((uint16_t)(mv.w & 0xffffu));
      acc[7] += zv * bf2f((uint16_t)(mv.w >> 16));
    }
    const float inv = 1.0f / Fn[b];
    float4* op = (float4*)(Out + (size_t)b*512 + n*32 + q*8);
    op[0] = make_float4(acc[0]*inv, acc[1]*inv, acc[2]*inv, acc[3]*inv);
    op[1] = make_float4(acc[4]*inv, acc[5]*inv, acc[6]*inv, acc[7]*inv);
  }
}

// ---------------- launch ----------------
extern "C" void kernel_launch(void* const* d_in, const int* in_sizes, int n_in,
                              void* d_out, int out_size, void* d_ws, size_t ws_size,
                              hipStream_t stream)
{
  const float* Z0    = (const float*)d_in[0];
  const float* h0    = (const float*)d_in[1];
  const float* mZ    = (const float*)d_in[2];
  const float* mh    = (const float*)d_in[3];
  const float* W_Z1  = (const float*)d_in[4];
  const float* W_h1  = (const float*)d_in[5];
  const float* b_h1  = (const float*)d_in[6];
  const float* W_g1a = (const float*)d_in[7];
  const float* b_g1a = (const float*)d_in[8];
  const float* W_g1b = (const float*)d_in[9];
  const float* b_g1b = (const float*)d_in[10];
  const float* W_Z2  = (const float*)d_in[11];
  const float* W1    = (const float*)d_in[12];
  const float* b1    = (const float*)d_in[13];
  const float* W2    = (const float*)d_in[14];
  const float* b2    = (const float*)d_in[15];
  const float* W3    = (const float*)d_in[16];
  const float* b3    = (const float*)d_in[17];

  char* ws = (char*)d_ws;
  size_t off = 0;
  auto alloc = [&](size_t bytes) -> char* {
    char* p = ws + off;
    off += (bytes + 255) & ~(size_t)255;
    return p;
  };
  uint16_t* W1t  = (uint16_t*)alloc((size_t)1024*1184*2);
  uint16_t* W2t  = (uint16_t*)alloc((size_t)1024*1024*2);
  uint16_t* W3t  = (uint16_t*)alloc((size_t)NPAD3*1024*2);
  float*    b3p  = (float*)   alloc((size_t)NPAD3*4);
  uint16_t* WfH  = (uint16_t*)alloc((size_t)6144*2);
  uint16_t* WfL  = (uint16_t*)alloc((size_t)6144*2);
  float*    wgG  = (float*)   alloc((size_t)32*4);
  float*    gate = (float*)   alloc((size_t)N_B*4);
  float*    Fn   = (float*)   alloc((size_t)N_B*4);
  uint16_t* Mcat = (uint16_t*)alloc((size_t)N_B*1184*2);
  uint16_t* H1   = (uint16_t*)alloc((size_t)N_B*1024*2);
  uint16_t* H2   = (uint16_t*)alloc((size_t)N_B*1024*2);
  uint16_t* Mzf  = Mcat;                          // Mcat dead after GEMM1 -> reuse
  float* OutMZ = (float*)d_out;
  float* OutMH = (float*)d_out + (size_t)N_B*512;

  transpose_cast_kernel<<<dim3(37,32), 256, 0, stream>>>(W1, W1t, 1184, 1024, 1024);
  transpose_cast_kernel<<<dim3(32,32), 256, 0, stream>>>(W2, W2t, 1024, 1024, 1024);
  transpose_cast_kernel<<<dim3(32,36), 256, 0, stream>>>(W3, W3t, 1024, 1056, NPAD3);
  prep_small_kernel<<<1, 256, 0, stream>>>(W_Z1, W_Z2, b3, WfH, WfL, wgG, b3p);
  gate_kernel<<<512, 256, 0, stream>>>(h0, mh, W_h1, b_h1, W_g1a, b_g1a, W_g1b, b_g1b,
                                       Mcat, gate);
  zm_gram_kernel<<<2048, 256, 0, stream>>>(Z0, mZ, WfH, WfL, wgG, gate, Mcat, Fn, OutMZ);
  gemm_kernel<37,1,0><<<dim3(256,8), 256, 0, stream>>>(Mcat, W1t, b1, H1, nullptr, nullptr);
  gemm_kernel<32,1,0><<<dim3(256,8), 256, 0, stream>>>(H1,   W2t, b2, H2, nullptr, nullptr);
  gemm_kernel<32,0,1><<<dim3(256,9), 256, 0, stream>>>(H2,   W3t, b3p, Mzf, OutMH, Fn);
  epilogue_kernel<<<2048, 256, 0, stream>>>(Mzf, Fn, OutMZ);
}

// Round 3
// 522.765 us; speedup vs baseline: 5.0735x; 1.3119x over previous
//
#include <hip/hip_runtime.h>
#include <stdint.h>

#define N_B    32768
#define MLPOUT 1056
#define MCAT_K 1216   // 1184 padded to 19*64
#define NPAD3  1280   // 1056 padded to 5*256

typedef __attribute__((ext_vector_type(8)))  __bf16 bf16x8;
typedef __attribute__((ext_vector_type(4)))  float  f32x4;
typedef __attribute__((ext_vector_type(16))) float  f32x16;

__device__ __forceinline__ uint16_t f2bf(float f){
  union { float f; uint32_t u; } v; v.f = f;
  return (uint16_t)((v.u + 0x7fffu + ((v.u >> 16) & 1u)) >> 16);
}
__device__ __forceinline__ float bf2f(uint16_t h){
  union { uint32_t u; float f; } v; v.u = ((uint32_t)h) << 16; return v.f;
}
__device__ __forceinline__ void gld_lds16(const void* gp, void* lp){
  __builtin_amdgcn_global_load_lds(
    (__attribute__((address_space(1))) void*)(void*)gp,
    (__attribute__((address_space(3))) void*)lp, 16, 0, 0);
}

// ---------------- k0a: f32 [K][N] -> bf16 [Npad][Kpad] transpose+cast+zero-pad ----------------
__global__ void transpose_cast_kernel(const float* __restrict__ in, uint16_t* __restrict__ out,
                                      int K, int N, int Kpad, int Npad)
{
  __shared__ float tile[32][33];
  const int tx = threadIdx.x & 31, ty = threadIdx.x >> 5;
  const int k0 = blockIdx.x * 32, n0 = blockIdx.y * 32;
#pragma unroll
  for (int i = 0; i < 4; i++){
    int k = k0 + ty + i*8, nn = n0 + tx;
    float v = (k < K && nn < N) ? in[(size_t)k*N + nn] : 0.0f;
    tile[ty + i*8][tx] = v;
  }
  __syncthreads();
#pragma unroll
  for (int i = 0; i < 4; i++){
    int nn = n0 + ty + i*8, k = k0 + tx;
    if (nn < Npad && k < Kpad) out[(size_t)nn*Kpad + k] = f2bf(tile[tx][ty + i*8]);
  }
}

// ---------------- k0b: fused W -> pre-packed MFMA B-fragments (hi/lo bf16) ----------------
__global__ void prep_small_kernel(const float* __restrict__ W_Z1, const float* __restrict__ W_Z2,
                                  const float* __restrict__ b3,
                                  uint16_t* __restrict__ WfH, uint16_t* __restrict__ WfL,
                                  float* __restrict__ wgG, float* __restrict__ b3p)
{
  __shared__ float wl[192*32];
  const int tid = threadIdx.x;
  for (int idx = tid; idx < 6144; idx += 256){
    int r = idx >> 5, c = idx & 31;
    float v;
    if (r < 64){
      v = 0.f;
      for (int i = 0; i < 32; i++) v += W_Z1[r*32 + i] * W_Z2[i*32 + c];
    } else v = W_Z2[(r - 32)*32 + c];
    wl[idx] = v;
  }
  __syncthreads();
  for (int q = tid; q < 768; q += 256){
    int lane = q & 63, ctkk = q >> 6;
    int ct = ctkk & 1, kk = ctkk >> 1;
    int c  = ct*16 + (lane & 15);
    int k0 = kk*32 + ((lane >> 4) << 3);
    for (int j = 0; j < 8; j++){
      float v = wl[(k0 + j)*32 + c];
      uint16_t hb = f2bf(v);
      WfH[q*8 + j] = hb;
      WfL[q*8 + j] = f2bf(v - bf2f(hb));
    }
  }
  if (tid < 32) wgG[tid] = W_Z2[160*32 + tid];
  for (int idx = tid; idx < NPAD3; idx += 256)
    b3p[idx] = (idx < MLPOUT) ? b3[idx] : 0.0f;
}

// ---------------- P1: h / hm / gate ----------------
__global__ __launch_bounds__(256)
void gate_kernel(const float* __restrict__ h0, const float* __restrict__ mh,
                 const float* __restrict__ W_h1, const float* __restrict__ b_h1,
                 const float* __restrict__ W_g1a, const float* __restrict__ b_g1a,
                 const float* __restrict__ W_g1b, const float* __restrict__ b_g1b,
                 uint16_t* __restrict__ Mcat, float* __restrict__ gateOut)
{
  __shared__ float wh[128*32];
  __shared__ float wg[160*32];
  __shared__ float wgb[32], bh[32], bga[32];
  __shared__ float bgb;
  __shared__ float hrow[4][128];
  __shared__ float hms[4][160];
  const int tid = threadIdx.x, w = tid >> 6, l = tid & 63;
  for (int i = tid; i < 4096; i += 256) wh[i] = W_h1[i];
  for (int i = tid; i < 5120; i += 256) wg[i] = W_g1a[i];
  if (tid < 32){ wgb[tid] = W_g1b[tid]; bh[tid] = b_h1[tid]; bga[tid] = b_g1a[tid]; }
  if (tid == 0) bgb = b_g1b[0];
  __syncthreads();
  const int cg = l & 31, kh = l >> 5;
  for (int bi = 0; bi < 16; bi++){
    const int b = blockIdx.x*64 + w*16 + bi;
    hrow[w][l]      = h0[(size_t)b*128 + l];
    hrow[w][64 + l] = h0[(size_t)b*128 + 64 + l];
    float mh0 = mh[(size_t)b*128 + l];
    float mh1 = mh[(size_t)b*128 + 64 + l];
    float hacc = 0.f;
#pragma unroll 16
    for (int i = 0; i < 64; i++){
      int k = kh*64 + i;
      hacc += hrow[w][k] * wh[k*32 + cg];
    }
    hacc += __shfl_xor(hacc, 32);
    float hmc = fmaxf(hacc + bh[cg], 0.f);
    float r0 = fmaxf(mh0, 0.f), r1 = fmaxf(mh1, 0.f);
    if (l < 32) hms[w][l] = hmc;
    hms[w][32 + l] = r0;
    hms[w][96 + l] = r1;
    uint16_t* mc = Mcat + (size_t)b*MCAT_K + 1024;
    if (l < 32) mc[l] = f2bf(hmc);
    mc[32 + l] = f2bf(r0);
    mc[96 + l] = f2bf(r1);
    if (l < 32) mc[160 + l] = 0;     // zero K-pad 1184..1215
    float tacc = 0.f;
#pragma unroll 16
    for (int i = 0; i < 80; i++){
      int k = kh*80 + i;
      tacc += hms[w][k] * wg[k*32 + cg];
    }
    tacc += __shfl_xor(tacc, 32);
    float tc = fmaxf(tacc + bga[cg], 0.f);
    float gp = (l < 32) ? tc * wgb[cg] : 0.f;
#pragma unroll
    for (int s = 1; s < 64; s <<= 1) gp += __shfl_xor(gp, s);
    if (l == 0) gateOut[b] = gp + bgb;
  }
}

// ---------------- P2: Zm (MFMA, compensated) + gram (MFMA) + F ----------------
__global__ __launch_bounds__(256)
void zm_gram_kernel(const float* __restrict__ Z0, const float* __restrict__ mZ,
                    const uint16_t* __restrict__ WfH, const uint16_t* __restrict__ WfL,
                    const float* __restrict__ wgG, const float* __restrict__ gateB,
                    uint16_t* __restrict__ Mcat, float* __restrict__ Fn,
                    float* __restrict__ ZmOut)
{
  __shared__ __align__(16) uint16_t wfh[6144], wfl[6144];
  __shared__ float wgs[32];
  __shared__ __align__(16) uint16_t zhS[4][32*24], zlS[4][32*24];
  const int tid = threadIdx.x, w = tid >> 6, l = tid & 63;
#pragma unroll
  for (int i = 0; i < 3; i++){
    gld_lds16(WfH + (i*256 + tid)*8, &wfh[(i*256 + w*64)*8]);
    gld_lds16(WfL + (i*256 + tid)*8, &wfl[(i*256 + w*64)*8]);
  }
  if (tid < 32) wgs[tid] = wgG[tid];
  __syncthreads();
  const int n = l & 15, sl = l >> 4;
  for (int bi = 0; bi < 4; bi++){
    const int b = (blockIdx.x << 4) + (w << 2) + bi;
    bf16x8 xh[6], xl[6];
    const float* zp = Z0 + (size_t)b*1024 + n*64  + sl*8;
    const float* mp = mZ + (size_t)b*2048 + n*128 + sl*8;
#pragma unroll
    for (int kk = 0; kk < 6; kk++){
      const float* src = (kk < 2) ? (zp + kk*32) : (mp + (kk - 2)*32);
      float x[8];
      *(float4*)&x[0] = *(const float4*)src;
      *(float4*)&x[4] = *(const float4*)(src + 4);
#pragma unroll
      for (int j = 0; j < 8; j++){
        __bf16 h = (__bf16)x[j];
        xh[kk][j] = h;
        xl[kk][j] = (__bf16)(x[j] - (float)h);
      }
    }
    f32x4 za[2];
    za[0] = (f32x4)(0.f); za[1] = (f32x4)(0.f);
#pragma unroll
    for (int kk = 0; kk < 6; kk++){
#pragma unroll
      for (int ct = 0; ct < 2; ct++){
        bf16x8 whf = *(const bf16x8*)&wfh[((kk*2 + ct)*64 + l)*8];
        bf16x8 wlf = *(const bf16x8*)&wfl[((kk*2 + ct)*64 + l)*8];
        za[ct] = __builtin_amdgcn_mfma_f32_16x16x32_bf16(xh[kk], whf, za[ct], 0, 0, 0);
        za[ct] = __builtin_amdgcn_mfma_f32_16x16x32_bf16(xl[kk], whf, za[ct], 0, 0, 0);
        za[ct] = __builtin_amdgcn_mfma_f32_16x16x32_bf16(xh[kk], wlf, za[ct], 0, 0, 0);
      }
    }
    const float g = gateB[b];
    if (sl == 0){
      za[0][2] += g * wgs[n];
      za[1][2] += g * wgs[16 + n];
    }
    float* zo = ZmOut + (size_t)b*512;
#pragma unroll
    for (int ct = 0; ct < 2; ct++){
      ushort4 ph, pl;
#pragma unroll
      for (int r = 0; r < 4; r++){
        float v = za[ct][r];
        zo[(sl*4 + r)*32 + ct*16 + n] = v;
        uint16_t hb = f2bf(v);
        ((uint16_t*)&ph)[r] = hb;
        ((uint16_t*)&pl)[r] = f2bf(v - bf2f(hb));
      }
      const int c = ct*16 + n;
      *(ushort4*)&zhS[w][c*24 + sl*4] = ph;
      *(ushort4*)&zlS[w][c*24 + sl*4] = pl;
    }
    const int c2 = l & 31, n0 = (l >> 5) << 3;
    bf16x8 zhf = *(const bf16x8*)&zhS[w][c2*24 + n0];
    bf16x8 zlf = *(const bf16x8*)&zlS[w][c2*24 + n0];
    f32x16 gacc = (f32x16)(0.f);
    gacc = __builtin_amdgcn_mfma_f32_32x32x16_bf16(zhf, zhf, gacc, 0, 0, 0);
    gacc = __builtin_amdgcn_mfma_f32_32x32x16_bf16(zlf, zhf, gacc, 0, 0, 0);
    gacc = __builtin_amdgcn_mfma_f32_32x32x16_bf16(zhf, zlf, gacc, 0, 0, 0);
    float fs = 0.f;
#pragma unroll
    for (int i = 0; i < 16; i++) fs += gacc[i]*gacc[i];
#pragma unroll
    for (int s = 1; s < 64; s <<= 1) fs += __shfl_xor(fs, s);
    if (l == 0) Fn[b] = sqrtf(fs) + 1.0f;
    uint16_t* mcb = Mcat + (size_t)b*MCAT_K;
#pragma unroll
    for (int r = 0; r < 16; r++){
      int row = (r & 3) + 8*(r >> 2) + 4*(l >> 5);
      mcb[row*32 + c2] = f2bf(gacc[r]);
    }
  }
}

// ---------------- 256x256 8-phase bf16 GEMM (T2 swizzle + T3/T4 counted vmcnt + T5) ----------------
// A [M][KK] bf16, Bt [Ntiles*256][KK] bf16. NT = KK/64 K-tiles.
// LDS halves (16KB each): A-half h = rows {0-63,128-191}+64h of tile; B-half h = n-sub h rows per wave group.
// Swizzle: 16B-chunk index within 128B row XORed with (row&7). Stage lands linear; source pre-swizzled.
template<int NT, int RELU, int MODE, int NTN>
__global__ __launch_bounds__(512)
void gemm8p_kernel(const uint16_t* __restrict__ A, const uint16_t* __restrict__ Bt,
                   const float* __restrict__ bias, uint16_t* __restrict__ outB,
                   float* __restrict__ outF, const float* __restrict__ Fn)
{
  constexpr int KK   = NT * 64;
  constexpr int NWG8 = (128 * NTN) / 8;
  __shared__ __align__(16) uint16_t lds[65536];   // 128 KiB: [buf][A/B][half][128*64]
  const int tid = threadIdx.x;
  const int w = tid >> 6, l = tid & 63;
  const int wr = w >> 2, wc = w & 3;
  const int rA = l & 15, kq = l >> 4, swz = rA & 7;
  const int wr64 = wr * 64, wc32 = wc * 32;
  const int cs0 = ((kq)     ^ swz) * 8;
  const int cs1 = ((4 + kq) ^ swz) * 8;
  // XCD-contiguous remap: XCD x owns 16 consecutive m-rows x all n  (A-panel L2 reuse)
  const int bid = blockIdx.x;
  const int tl  = (bid & 7) * NWG8 + (bid >> 3);
  const int m0  = (tl / NTN) * 256, n0 = (tl % NTN) * 256;

  f32x4 acc[8][4];
#pragma unroll
  for (int f = 0; f < 8; f++)
#pragma unroll
    for (int g = 0; g < 4; g++) acc[f][g] = (f32x4)(0.0f);
  uint4 aF[4][2], bF0[2][2], bF1[2][2];

#define STAGE_A(bf_, hf_, kt_) do{ \
  _Pragma("unroll") for (int j_ = 0; j_ < 2; j_++){ \
    int sl_ = j_*512 + tid; int r_ = sl_ >> 3; int c_ = (sl_ & 7) ^ (r_ & 7); \
    int rg_ = ((r_ >> 6) << 7) + (hf_)*64 + (r_ & 63); \
    gld_lds16(A + (size_t)(m0 + rg_)*KK + (kt_)*64 + c_*8, \
              &lds[(bf_)*32768 + (hf_)*8192 + (j_*512 + w*64)*8]); } }while(0)
#define STAGE_B(bf_, hf_, kt_) do{ \
  _Pragma("unroll") for (int j_ = 0; j_ < 2; j_++){ \
    int sl_ = j_*512 + tid; int r_ = sl_ >> 3; int c_ = (sl_ & 7) ^ (r_ & 7); \
    int rg_ = ((r_ >> 5) << 6) + (hf_)*32 + (r_ & 31); \
    gld_lds16(Bt + (size_t)(n0 + rg_)*KK + (kt_)*64 + c_*8, \
              &lds[(bf_)*32768 + 16384 + (hf_)*8192 + (j_*512 + w*64)*8]); } }while(0)
#define RD_A(bf_, hf_) do{ _Pragma("unroll") for (int ff_ = 0; ff_ < 4; ff_++){ \
    int ro_ = (bf_)*32768 + (hf_)*8192 + (wr64 + ff_*16 + rA)*64; \
    aF[ff_][0] = *(const uint4*)&lds[ro_ + cs0]; \
    aF[ff_][1] = *(const uint4*)&lds[ro_ + cs1]; } }while(0)
#define RD_B(dst_, bf_, hf_) do{ _Pragma("unroll") for (int gg_ = 0; gg_ < 2; gg_++){ \
    int ro_ = (bf_)*32768 + 16384 + (hf_)*8192 + (wc32 + gg_*16 + rA)*64; \
    dst_[gg_][0] = *(const uint4*)&lds[ro_ + cs0]; \
    dst_[gg_][1] = *(const uint4*)&lds[ro_ + cs1]; } }while(0)
#define MFMA16(ms_, ns_, B_) do{ _Pragma("unroll") for (int ff_ = 0; ff_ < 4; ff_++) \
  _Pragma("unroll") for (int gg_ = 0; gg_ < 2; gg_++){ \
    acc[(ms_)*4+ff_][(ns_)*2+gg_] = __builtin_amdgcn_mfma_f32_16x16x32_bf16( \
      __builtin_bit_cast(bf16x8, aF[ff_][0]), __builtin_bit_cast(bf16x8, B_[gg_][0]), \
      acc[(ms_)*4+ff_][(ns_)*2+gg_], 0, 0, 0); \
    acc[(ms_)*4+ff_][(ns_)*2+gg_] = __builtin_amdgcn_mfma_f32_16x16x32_bf16( \
      __builtin_bit_cast(bf16x8, aF[ff_][1]), __builtin_bit_cast(bf16x8, B_[gg_][1]), \
      acc[(ms_)*4+ff_][(ns_)*2+gg_], 0, 0, 0); } }while(0)
#define BAR()   __builtin_amdgcn_s_barrier()
#define LGKM0() asm volatile("s_waitcnt lgkmcnt(0)" ::: "memory")

  // prologue: tile0 h0..h3 (8 loads) + tile1 h0,h1,h2 (6 loads); wait 8 oldest -> tile0 landed
  STAGE_A(0, 0, 0); STAGE_B(0, 0, 0); STAGE_A(0, 1, 0); STAGE_B(0, 1, 0);
  STAGE_A(1, 0, 1); STAGE_B(1, 0, 1); STAGE_A(1, 1, 1);
  asm volatile("s_waitcnt vmcnt(6)" ::: "memory");
  BAR();

  for (int t = 0; t < NT; t++){
    const int buf = t & 1, bufn = buf ^ 1;
    // phase 0: read A msub0 + B nsub0; stage (t+1).h3 = B-half1 (other buf)
    RD_A(buf, 0); RD_B(bF0, buf, 0);
    if (t + 1 < NT) STAGE_B(bufn, 1, t + 1);
    BAR(); LGKM0();
    __builtin_amdgcn_s_setprio(1); MFMA16(0, 0, bF0); __builtin_amdgcn_s_setprio(0);
    BAR();
    // phase 1: read B nsub1; stage (t+2).h0 = A-half0 (current buf; its last read was phase 0)
    RD_B(bF1, buf, 1);
    if (t + 2 < NT) STAGE_A(buf, 0, t + 2);
    BAR(); LGKM0();
    __builtin_amdgcn_s_setprio(1); MFMA16(0, 1, bF1); __builtin_amdgcn_s_setprio(0);
    BAR();
    // phase 2: read A msub1; stage (t+2).h1 = B-half0 (last read phase 0; bF0 kept in regs)
    RD_A(buf, 1);
    if (t + 2 < NT) STAGE_B(buf, 0, t + 2);
    BAR(); LGKM0();
    __builtin_amdgcn_s_setprio(1); MFMA16(1, 0, bF0); __builtin_amdgcn_s_setprio(0);
    BAR();
    // phase 3: no reads; stage (t+2).h2 = A-half1 (last read phase 2)
    if (t + 2 < NT) STAGE_A(buf, 1, t + 2);
    BAR();
    __builtin_amdgcn_s_setprio(1); MFMA16(1, 1, bF1); __builtin_amdgcn_s_setprio(0);
    if (t < NT - 2)       { asm volatile("s_waitcnt vmcnt(6)" ::: "memory"); }
    else if (t == NT - 2) { asm volatile("s_waitcnt vmcnt(0)" ::: "memory"); }
    BAR();
  }
#undef STAGE_A
#undef STAGE_B
#undef RD_A
#undef RD_B
#undef MFMA16
#undef BAR
#undef LGKM0

  // epilogue: C/D layout col = l&15, row = (l>>4)*4 + i
#pragma unroll
  for (int f = 0; f < 8; f++){
    int grow0 = m0 + wr*128 + f*16 + kq*4;
#pragma unroll
    for (int g = 0; g < 4; g++){
      int gcol = n0 + wc*64 + g*16 + rA;
      float bv = bias[gcol];
#pragma unroll
      for (int i = 0; i < 4; i++){
        float v = acc[f][g][i] + bv;
        if (RELU) v = fmaxf(v, 0.0f);
        int grow = grow0 + i;
        if (MODE == 0){
          outB[(size_t)grow*1024 + gcol] = f2bf(v);
        } else {
          if (gcol < 1024)      outB[(size_t)grow*1024 + gcol] = f2bf(v);
          else if (gcol < 1056) outF[(size_t)grow*32 + (gcol - 1024)] = v / Fn[grow];
        }
      }
    }
  }
}

// ---------------- k5: M_Z = (Zm @ M_Zflat) / F ----------------
__global__ __launch_bounds__(256)
void epilogue_kernel(const uint16_t* __restrict__ Mzf, const float* __restrict__ Fn,
                     float* __restrict__ Out)
{
  __shared__ __align__(16) uint16_t mzS[4][1024];
  __shared__ __align__(16) float    zmS[4][16*36];
  const int tid = threadIdx.x, w = tid >> 6, l = tid & 63;
  const int n = l & 15, q = l >> 4;
  for (int bi = 0; bi < 4; bi++){
    const int b = (blockIdx.x << 4) + (w << 2) + bi;
    const uint4* src = (const uint4*)(Mzf + (size_t)b*1024);
    uint4* dst = (uint4*)&mzS[w][0];
    dst[l]      = src[l];
    dst[l + 64] = src[l + 64];
    const float4* zsrc = (const float4*)(Out + (size_t)b*512);
#pragma unroll
    for (int i = 0; i < 2; i++){
      int f = i*64 + l;
      int nn = f >> 3, c4 = f & 7;
      *(float4*)&zmS[w][nn*36 + c4*4] = zsrc[f];
    }
    float acc[8];
#pragma unroll
    for (int i = 0; i < 8; i++) acc[i] = 0.f;
#pragma unroll
    for (int j = 0; j < 32; j++){
      float zv = zmS[w][n*36 + j];
      uint4 mv = *(const uint4*)&mzS[w][j*32 + q*8];
      acc[0] += zv * bf2f((uint16_t)(mv.x & 0xffffu));
      acc[1] += zv * bf2f((uint16_t)(mv.x >> 16));
      acc[2] += zv * bf2f((uint16_t)(mv.y & 0xffffu));
      acc[3] += zv * bf2f((uint16_t)(mv.y >> 16));
      acc[4] += zv * bf2f((uint16_t)(mv.z & 0xffffu));
      acc[5] += zv * bf2f((uint16_t)(mv.z >> 16));
      acc[6] += zv * bf2f((uint16_t)(mv.w & 0xffffu));
      acc[7] += zv * bf2f((uint16_t)(mv.w >> 16));
    }
    const float inv = 1.0f / Fn[b];
    float4* op = (float4*)(Out + (size_t)b*512 + n*32 + q*8);
    op[0] = make_float4(acc[0]*inv, acc[1]*inv, acc[2]*inv, acc[3]*inv);
    op[1] = make_float4(acc[4]*inv, acc[5]*inv, acc[6]*inv, acc[7]*inv);
  }
}

// ---------------- launch ----------------
extern "C" void kernel_launch(void* const* d_in, const int* in_sizes, int n_in,
                              void* d_out, int out_size, void* d_ws, size_t ws_size,
                              hipStream_t stream)
{
  const float* Z0    = (const float*)d_in[0];
  const float* h0    = (const float*)d_in[1];
  const float* mZ    = (const float*)d_in[2];
  const float* mh    = (const float*)d_in[3];
  const float* W_Z1  = (const float*)d_in[4];
  const float* W_h1  = (const float*)d_in[5];
  const float* b_h1  = (const float*)d_in[6];
  const float* W_g1a = (const float*)d_in[7];
  const float* b_g1a = (const float*)d_in[8];
  const float* W_g1b = (const float*)d_in[9];
  const float* b_g1b = (const float*)d_in[10];
  const float* W_Z2  = (const float*)d_in[11];
  const float* W1    = (const float*)d_in[12];
  const float* b1    = (const float*)d_in[13];
  const float* W2    = (const float*)d_in[14];
  const float* b2    = (const float*)d_in[15];
  const float* W3    = (const float*)d_in[16];
  const float* b3    = (const float*)d_in[17];

  char* ws = (char*)d_ws;
  size_t off = 0;
  auto alloc = [&](size_t bytes) -> char* {
    char* p = ws + off;
    off += (bytes + 255) & ~(size_t)255;
    return p;
  };
  uint16_t* W1t  = (uint16_t*)alloc((size_t)1024*MCAT_K*2);
  uint16_t* W2t  = (uint16_t*)alloc((size_t)1024*1024*2);
  uint16_t* W3t  = (uint16_t*)alloc((size_t)NPAD3*1024*2);
  float*    b3p  = (float*)   alloc((size_t)NPAD3*4);
  uint16_t* WfH  = (uint16_t*)alloc((size_t)6144*2);
  uint16_t* WfL  = (uint16_t*)alloc((size_t)6144*2);
  float*    wgG  = (float*)   alloc((size_t)32*4);
  float*    gate = (float*)   alloc((size_t)N_B*4);
  float*    Fn   = (float*)   alloc((size_t)N_B*4);
  uint16_t* Mcat = (uint16_t*)alloc((size_t)N_B*MCAT_K*2);
  uint16_t* H1   = (uint16_t*)alloc((size_t)N_B*1024*2);
  uint16_t* H2   = (uint16_t*)alloc((size_t)N_B*1024*2);
  uint16_t* Mzf  = Mcat;                          // Mcat dead after GEMM1 -> reuse (stride 1024)
  float* OutMZ = (float*)d_out;
  float* OutMH = (float*)d_out + (size_t)N_B*512;

  transpose_cast_kernel<<<dim3(38,32), 256, 0, stream>>>(W1, W1t, 1184, 1024, MCAT_K, 1024);
  transpose_cast_kernel<<<dim3(32,32), 256, 0, stream>>>(W2, W2t, 1024, 1024, 1024, 1024);
  transpose_cast_kernel<<<dim3(32,40), 256, 0, stream>>>(W3, W3t, 1024, 1056, 1024, NPAD3);
  prep_small_kernel<<<1, 256, 0, stream>>>(W_Z1, W_Z2, b3, WfH, WfL, wgG, b3p);
  gate_kernel<<<512, 256, 0, stream>>>(h0, mh, W_h1, b_h1, W_g1a, b_g1a, W_g1b, b_g1b,
                                       Mcat, gate);
  zm_gram_kernel<<<2048, 256, 0, stream>>>(Z0, mZ, WfH, WfL, wgG, gate, Mcat, Fn, OutMZ);
  gemm8p_kernel<19,1,0,4><<<512, 512, 0, stream>>>(Mcat, W1t, b1, H1, nullptr, nullptr);
  gemm8p_kernel<16,1,0,4><<<512, 512, 0, stream>>>(H1,   W2t, b2, H2, nullptr, nullptr);
  gemm8p_kernel<16,0,1,5><<<640, 512, 0, stream>>>(H2,   W3t, b3p, Mzf, OutMH, Fn);
  epilogue_kernel<<<2048, 256, 0, stream>>>(Mzf, Fn, OutMZ);
}